// Round 3
// baseline (2705.951 us; speedup 1.0000x reference)
//
#include <hip/hip_runtime.h>
#include <cstdint>
#include <cstddef>

#define B_  2
#define L_  1024
#define DM  2048
#define DI  4096
#define DSZ 16
#define RR  128

__device__ __forceinline__ float siluf(float v) {
    return v / (1.f + __expf(-v));
}
__device__ __forceinline__ float softplusf(float v) {
    // stable: max(v,0) + log1p(exp(-|v|))
    return fmaxf(v, 0.f) + log1pf(__expf(-fabsf(v)));
}

// C[m][n] = sum_k A[m*lda+k] * B[n*ldb+k]   ("NT": both K-contiguous)
// 64x64 tile, K-step 16, 256 threads, 4x4 per thread.
// EPI==1: v = softplus(v + bias[n])
template<int EPI>
__global__ __launch_bounds__(256)
void gemm_nt(const float* __restrict__ A, int lda,
             const float* __restrict__ Bw, int ldb,
             float* __restrict__ C, int ldc,
             int N, int K, const float* __restrict__ bias)
{
    __shared__ float As[16][64];   // [k][m]
    __shared__ float Bs[16][64];   // [k][n]
    const int t  = threadIdx.x;
    const int m0 = blockIdx.y * 64;
    const int n0 = blockIdx.x * 64;
    const int lr = t >> 2;          // 0..63 row within tile
    const int lc = (t & 3) << 2;    // 0,4,8,12 k within tile
    const int ty = t >> 4;          // 0..15
    const int tx = t & 15;          // 0..15
    float acc[4][4] = {};

    const float* aP = A  + (size_t)(m0 + lr) * lda + lc;
    const float* bP = Bw + (size_t)(n0 + lr) * ldb + lc;
    const bool bok = (n0 + lr) < N;

    for (int k0 = 0; k0 < K; k0 += 16) {
        float4 av = *(const float4*)(aP + k0);
        float4 bv = make_float4(0.f, 0.f, 0.f, 0.f);
        if (bok) bv = *(const float4*)(bP + k0);
        __syncthreads();
        As[lc+0][lr] = av.x; As[lc+1][lr] = av.y; As[lc+2][lr] = av.z; As[lc+3][lr] = av.w;
        Bs[lc+0][lr] = bv.x; Bs[lc+1][lr] = bv.y; Bs[lc+2][lr] = bv.z; Bs[lc+3][lr] = bv.w;
        __syncthreads();
        #pragma unroll
        for (int kk = 0; kk < 16; ++kk) {
            float4 a4 = *(const float4*)&As[kk][ty << 2];
            float4 b4 = *(const float4*)&Bs[kk][tx << 2];
            float a[4] = {a4.x, a4.y, a4.z, a4.w};
            float b[4] = {b4.x, b4.y, b4.z, b4.w};
            #pragma unroll
            for (int i = 0; i < 4; ++i)
                #pragma unroll
                for (int j = 0; j < 4; ++j)
                    acc[i][j] = fmaf(a[i], b[j], acc[i][j]);
        }
    }

    #pragma unroll
    for (int i = 0; i < 4; ++i) {
        const int m = m0 + (ty << 2) + i;
        const int n = n0 + (tx << 2);
        if (n < N) {
            float4 o;
            float* po = (float*)&o;
            #pragma unroll
            for (int j = 0; j < 4; ++j) {
                float v = acc[i][j];
                if (EPI == 1) v = softplusf(v + bias[n + j]);
                po[j] = v;
            }
            *(float4*)(C + (size_t)m * ldc + n) = o;
        }
    }
}

// Depthwise causal conv (width 4) + bias + SiLU.
// x[b,d,l] = proj[b,l,d] (d < DI).  Output xconv[(b*L+l)*DI + d].
__global__ __launch_bounds__(256)
void conv_silu_k(const float* __restrict__ proj, const float* __restrict__ w,
                 const float* __restrict__ bias, float* __restrict__ xconv)
{
    const int idx = blockIdx.x * 256 + threadIdx.x;   // over B*L*DI, d fastest
    const int d  = idx & (DI - 1);
    const int bl = idx >> 12;           // b*L + l
    const int l  = bl & (L_ - 1);
    const float* pp = proj + (size_t)bl * (2 * DI) + d;
    float acc = bias[d];
    #pragma unroll
    for (int j = 0; j < 4; ++j) {
        const int ls = l - 3 + j;
        if (ls >= 0)
            acc = fmaf(w[(d << 2) + j], pp[(ptrdiff_t)(j - 3) * (2 * DI)], acc);
    }
    xconv[idx] = siluf(acc);
}

// Selective scan. 16 lanes per (b,d) channel, lane = state n.
// dy: delta on input, y on output (in-place, same wave owns both).
__global__ __launch_bounds__(256)
void scan_k(float* __restrict__ dy,
            const float* __restrict__ xconv,
            const float* __restrict__ xdbl,
            const float* __restrict__ proj,   // z = proj[b,l,DI+d]
            const float* __restrict__ A_log,
            const float* __restrict__ Dp)
{
    const int bi = blockIdx.x;            // 0..511
    const int b  = bi >> 8;
    const int t  = threadIdx.x;
    const int n  = t & 15;
    const int d  = ((bi & 255) << 4) + (t >> 4);   // 16 channels / block

    const float An = -__expf(A_log[(d << 4) + n]);
    const float Dd = Dp[d];
    float h = 0.f;

    for (int l = 0; l < L_; ++l) {
        const size_t roff = (size_t)((b << 10) | l);
        const float dlt = dy[roff * DI + d];
        const float uu  = xconv[roff * DI + d];
        const float bn  = xdbl[roff * 160 + 128 + n];
        const float cn  = xdbl[roff * 160 + 144 + n];
        const float dA  = __expf(dlt * An);
        h = fmaf(dA, h, dlt * uu * bn);
        float p = h * cn;
        p += __shfl_xor(p, 1);
        p += __shfl_xor(p, 2);
        p += __shfl_xor(p, 4);
        p += __shfl_xor(p, 8);
        if (n == 0) {
            const float zz = proj[roff * (2 * DI) + DI + d];
            dy[roff * DI + d] = (p + uu * Dd) * siluf(zz);
        }
    }
}

extern "C" void kernel_launch(void* const* d_in, const int* in_sizes, int n_in,
                              void* d_out, int out_size, void* d_ws, size_t ws_size,
                              hipStream_t stream)
{
    const float* hs    = (const float*)d_in[1];
    const float* Win   = (const float*)d_in[2];
    const float* convw = (const float*)d_in[3];
    const float* convb = (const float*)d_in[4];
    const float* Wx    = (const float*)d_in[5];
    const float* Wdt   = (const float*)d_in[6];
    const float* bdt   = (const float*)d_in[7];
    const float* Wout  = (const float*)d_in[8];
    const float* Alog  = (const float*)d_in[9];
    const float* Dp    = (const float*)d_in[10];

    float* out   = (float*)d_out;                    // (2,1024,2048)
    float* proj  = out + (size_t)B_ * L_ * DM;       // (2,1024,8192) = output 1
    float* xconv = (float*)d_ws;                     // (2048, 4096)
    float* xdbl  = xconv + (size_t)B_ * L_ * DI;     // (2048, 160)
    float* dy    = xdbl + (size_t)B_ * L_ * 160;     // (2048, 4096) delta -> y

    const int M = B_ * L_;

    // 1) proj = hs @ Win^T   (M=2048, N=8192, K=2048)
    gemm_nt<0><<<dim3((2 * DI) / 64, M / 64), 256, 0, stream>>>(
        hs, DM, Win, DM, proj, 2 * DI, 2 * DI, DM, nullptr);

    // 2) depthwise conv + bias + SiLU -> xconv
    conv_silu_k<<<(B_ * L_ * DI) / 256, 256, 0, stream>>>(proj, convw, convb, xconv);

    // 3) x_dbl = xconv @ Wx^T   (N=160, K=4096)
    gemm_nt<0><<<dim3(3, M / 64), 256, 0, stream>>>(
        xconv, DI, Wx, DI, xdbl, 160, 160, DI, nullptr);

    // 4) delta = softplus(dt @ Wdt^T + bdt)   (N=4096, K=128, lda=160)
    gemm_nt<1><<<dim3(DI / 64, M / 64), 256, 0, stream>>>(
        xdbl, 160, Wdt, RR, dy, DI, DI, RR, bdt);

    // 5) selective scan + D-skip + SiLU(z) gate, in-place delta->y
    scan_k<<<512, 256, 0, stream>>>(dy, xconv, xdbl, proj, Alog, Dp);

    // 6) out = y @ Wout^T   (N=2048, K=4096)
    gemm_nt<0><<<dim3(DM / 64, M / 64), 256, 0, stream>>>(
        dy, DI, Wout, DI, out, DM, DM, DI, nullptr);
}

// Round 6
// 1468.451 us; speedup vs baseline: 1.8427x; 1.8427x over previous
//
#include <hip/hip_runtime.h>
#include <cstdint>
#include <cstddef>

#define B_  2
#define L_  1024
#define DM  2048
#define DI  4096
#define RR  128

using short8 = __attribute__((ext_vector_type(8))) short;
using f32x4  = __attribute__((ext_vector_type(4))) float;

__device__ __forceinline__ float siluf(float v) {
    return v / (1.f + __expf(-v));
}
__device__ __forceinline__ float softplusf(float v) {
    return fmaxf(v, 0.f) + log1pf(__expf(-fabsf(v)));
}
// fp32 -> bf16 bits, round-to-nearest-even (finite inputs)
__device__ __forceinline__ unsigned short f2bf(float f) {
    unsigned u = __builtin_bit_cast(unsigned, f);
    u += 0x7fffu + ((u >> 16) & 1u);
    return (unsigned short)(u >> 16);
}

// ---------------- cast fp32 -> bf16, 8 elems/thread ----------------
__global__ __launch_bounds__(256)
void cast_bf16_k(const float* __restrict__ s, unsigned short* __restrict__ d, int n8)
{
    const int i = blockIdx.x * 256 + threadIdx.x;
    if (i >= n8) return;
    const float4* sp = (const float4*)s;
    const float4 a = sp[2 * i];
    const float4 b = sp[2 * i + 1];
    short8 o;
    o[0] = (short)f2bf(a.x); o[1] = (short)f2bf(a.y);
    o[2] = (short)f2bf(a.z); o[3] = (short)f2bf(a.w);
    o[4] = (short)f2bf(b.x); o[5] = (short)f2bf(b.y);
    o[6] = (short)f2bf(b.z); o[7] = (short)f2bf(b.w);
    *(short8*)(d + (size_t)i * 8) = o;
}

// ---------------- bf16 MFMA GEMM (NT): C[m][n] = sum_k A[m][k]*B[n][k] ----------------
// 128x128 tile, BK=32, 256 threads (4 waves, 2x2 quadrants of 64x64),
// global_load_lds width=16 staging, mfma_f32_16x16x32_bf16.
// M,N fixed by grid (multiples of 128); K multiple of 32.
__global__ __launch_bounds__(256)
void gemm_bf16_mfma(const unsigned short* __restrict__ A16,  // [M][K] bf16 bits
                    const unsigned short* __restrict__ B16,  // [N][K] bf16 bits
                    float* __restrict__ C, int ldc, int K)
{
    __shared__ unsigned short As[128 * 32];   // [row][k], 64 B/row, linear
    __shared__ unsigned short Bs[128 * 32];
    const int t  = threadIdx.x;
    const int w  = t >> 6;          // wave 0..3
    const int l  = t & 63;
    const int m0 = blockIdx.y * 128;
    const int n0 = blockIdx.x * 128;
    const int wr = w >> 1, wc = w & 1;       // 64x64 quadrant
    const int lm = l & 15, lk = l >> 4;      // fragment lane coords

    f32x4 acc[4][4] = {};

    for (int k0 = 0; k0 < K; k0 += 32) {
        // stage A,B tiles: per wave 2 chunk-blocks each; chunk c = 16B,
        // row = c>>2, col16 = c&3. LDS dest = base + cb*1024B (wave-uniform).
        #pragma unroll
        for (int i = 0; i < 2; ++i) {
            const int cb  = w * 2 + i;
            const int c   = cb * 64 + l;
            const int row = c >> 2, c16 = c & 3;
            const unsigned short* ga = A16 + (size_t)(m0 + row) * K + k0 + c16 * 8;
            const unsigned short* gb = B16 + (size_t)(n0 + row) * K + k0 + c16 * 8;
            __builtin_amdgcn_global_load_lds((const __attribute__((address_space(1))) void*)ga,
                                             (__attribute__((address_space(3))) void*)(As + cb * 512),
                                             16, 0, 0);
            __builtin_amdgcn_global_load_lds((const __attribute__((address_space(1))) void*)gb,
                                             (__attribute__((address_space(3))) void*)(Bs + cb * 512),
                                             16, 0, 0);
        }
        __syncthreads();   // compiler drains vmcnt before barrier

        short8 aF[4], bF[4];
        #pragma unroll
        for (int m = 0; m < 4; ++m)
            aF[m] = *(const short8*)(As + (wr * 64 + m * 16 + lm) * 32 + lk * 8);
        #pragma unroll
        for (int n = 0; n < 4; ++n)
            bF[n] = *(const short8*)(Bs + (wc * 64 + n * 16 + lm) * 32 + lk * 8);
        #pragma unroll
        for (int m = 0; m < 4; ++m)
            #pragma unroll
            for (int n = 0; n < 4; ++n)
                acc[m][n] = __builtin_amdgcn_mfma_f32_16x16x32_bf16(aF[m], bF[n], acc[m][n], 0, 0, 0);
        __syncthreads();
    }

    // C/D layout: col = lane&15, row = (lane>>4)*4 + reg
    const int cm = m0 + wr * 64 + (l >> 4) * 4;
    const int cn = n0 + wc * 64 + lm;
    #pragma unroll
    for (int m = 0; m < 4; ++m)
        #pragma unroll
        for (int n = 0; n < 4; ++n)
            #pragma unroll
            for (int r = 0; r < 4; ++r)
                C[(size_t)(cm + m * 16 + r) * ldc + cn + n * 16] = acc[m][n][r];
}

// ---------------- fp32 tiled GEMM (NT) for the small projections ----------------
template<int EPI>
__global__ __launch_bounds__(256)
void gemm_nt(const float* __restrict__ A, int lda,
             const float* __restrict__ Bw, int ldb,
             float* __restrict__ C, int ldc,
             int N, int K, const float* __restrict__ bias)
{
    __shared__ float As[16][64];
    __shared__ float Bs[16][64];
    const int t  = threadIdx.x;
    const int m0 = blockIdx.y * 64;
    const int n0 = blockIdx.x * 64;
    const int lr = t >> 2;
    const int lc = (t & 3) << 2;
    const int ty = t >> 4;
    const int tx = t & 15;
    float acc[4][4] = {};

    const float* aP = A  + (size_t)(m0 + lr) * lda + lc;
    const float* bP = Bw + (size_t)(n0 + lr) * ldb + lc;
    const bool bok = (n0 + lr) < N;

    for (int k0 = 0; k0 < K; k0 += 16) {
        float4 av = *(const float4*)(aP + k0);
        float4 bv = make_float4(0.f, 0.f, 0.f, 0.f);
        if (bok) bv = *(const float4*)(bP + k0);
        __syncthreads();
        As[lc+0][lr] = av.x; As[lc+1][lr] = av.y; As[lc+2][lr] = av.z; As[lc+3][lr] = av.w;
        Bs[lc+0][lr] = bv.x; Bs[lc+1][lr] = bv.y; Bs[lc+2][lr] = bv.z; Bs[lc+3][lr] = bv.w;
        __syncthreads();
        #pragma unroll
        for (int kk = 0; kk < 16; ++kk) {
            float4 a4 = *(const float4*)&As[kk][ty << 2];
            float4 b4 = *(const float4*)&Bs[kk][tx << 2];
            float a[4] = {a4.x, a4.y, a4.z, a4.w};
            float b[4] = {b4.x, b4.y, b4.z, b4.w};
            #pragma unroll
            for (int i = 0; i < 4; ++i)
                #pragma unroll
                for (int j = 0; j < 4; ++j)
                    acc[i][j] = fmaf(a[i], b[j], acc[i][j]);
        }
    }

    #pragma unroll
    for (int i = 0; i < 4; ++i) {
        const int m = m0 + (ty << 2) + i;
        const int n = n0 + (tx << 2);
        if (n < N) {
            float4 o;
            float* po = (float*)&o;
            #pragma unroll
            for (int j = 0; j < 4; ++j) {
                float v = acc[i][j];
                if (EPI == 1) v = softplusf(v + bias[n + j]);
                po[j] = v;
            }
            *(float4*)(C + (size_t)m * ldc + n) = o;
        }
    }
}

// ---------------- depthwise causal conv(4) + bias + SiLU ----------------
__global__ __launch_bounds__(256)
void conv_silu_k(const float* __restrict__ proj, const float* __restrict__ w,
                 const float* __restrict__ bias, float* __restrict__ xconv)
{
    const int idx = blockIdx.x * 256 + threadIdx.x;
    const int d  = idx & (DI - 1);
    const int bl = idx >> 12;
    const int l  = bl & (L_ - 1);
    const float* pp = proj + (size_t)bl * (2 * DI) + d;
    float acc = bias[d];
    #pragma unroll
    for (int j = 0; j < 4; ++j) {
        const int ls = l - 3 + j;
        if (ls >= 0)
            acc = fmaf(w[(d << 2) + j], pp[(ptrdiff_t)(j - 3) * (2 * DI)], acc);
    }
    xconv[idx] = siluf(acc);
}

// ---------------- selective scan; emits gated y as bf16 ----------------
__global__ __launch_bounds__(256)
void scan_k(const float* __restrict__ dlt,
            const float* __restrict__ xconv,
            const float* __restrict__ xdbl,
            const float* __restrict__ proj,     // z = proj[b,l,DI+d]
            const float* __restrict__ A_log,
            const float* __restrict__ Dp,
            unsigned short* __restrict__ y16)
{
    const int bi = blockIdx.x;            // 0..511
    const int b  = bi >> 8;
    const int t  = threadIdx.x;
    const int n  = t & 15;
    const int d  = ((bi & 255) << 4) + (t >> 4);

    const float An = -__expf(A_log[(d << 4) + n]);
    const float Dd = Dp[d];
    float h = 0.f;

    for (int l = 0; l < L_; ++l) {
        const size_t roff = (size_t)((b << 10) | l);
        const float dv = dlt[roff * DI + d];
        const float uu = xconv[roff * DI + d];
        const float bn = xdbl[roff * 160 + 128 + n];
        const float cn = xdbl[roff * 160 + 144 + n];
        const float dA = __expf(dv * An);
        h = fmaf(dA, h, dv * uu * bn);
        float p = h * cn;
        p += __shfl_xor(p, 1);
        p += __shfl_xor(p, 2);
        p += __shfl_xor(p, 4);
        p += __shfl_xor(p, 8);
        if (n == 0) {
            const float zz = proj[roff * (2 * DI) + DI + d];
            y16[roff * DI + d] = f2bf((p + uu * Dd) * siluf(zz));
        }
    }
}

extern "C" void kernel_launch(void* const* d_in, const int* in_sizes, int n_in,
                              void* d_out, int out_size, void* d_ws, size_t ws_size,
                              hipStream_t stream)
{
    const float* hs    = (const float*)d_in[1];
    const float* Win   = (const float*)d_in[2];
    const float* convw = (const float*)d_in[3];
    const float* convb = (const float*)d_in[4];
    const float* Wx    = (const float*)d_in[5];
    const float* Wdt   = (const float*)d_in[6];
    const float* bdt   = (const float*)d_in[7];
    const float* Wout  = (const float*)d_in[8];
    const float* Alog  = (const float*)d_in[9];
    const float* Dp    = (const float*)d_in[10];

    float* out  = (float*)d_out;                    // (2,1024,2048)
    float* proj = out + (size_t)B_ * L_ * DM;       // (2,1024,8192) = output 1

    // ws overlays (stream-ordered lifetimes):
    //  o0: Win16 (33.5MB, dead after in_proj) -> xconv fp32 (33.5MB)
    //  o1: xdbl fp32 (1.31MB)
    //  o2: delta fp32 (33.5MB, dead after scan) -> Wout16 (16.8MB)
    //  o3: hs16 (8.4MB, dead after in_proj) -> y16 (16.8MB)
    char* ws = (char*)d_ws;
    unsigned short* Win16  = (unsigned short*)ws;
    float*          xconv  = (float*)ws;
    float*          xdbl   = (float*)(ws + 33554432);
    float*          dlt    = (float*)(ws + 34865152);
    unsigned short* Wout16 = (unsigned short*)(ws + 34865152);
    unsigned short* hs16   = (unsigned short*)(ws + 68419584);
    unsigned short* y16    = (unsigned short*)(ws + 68419584);

    const int M = B_ * L_;   // 2048

    // casts for in_proj
    cast_bf16_k<<<(M * DM / 8 + 255) / 256, 256, 0, stream>>>(hs, hs16, M * DM / 8);
    cast_bf16_k<<<(2 * DI * DM / 8 + 255) / 256, 256, 0, stream>>>(Win, Win16, 2 * DI * DM / 8);

    // 1) proj = hs @ Win^T   (M=2048, N=8192, K=2048)  [bf16 MFMA]
    gemm_bf16_mfma<<<dim3((2 * DI) / 128, M / 128), 256, 0, stream>>>(
        hs16, Win16, proj, 2 * DI, DM);

    // 2) depthwise conv + bias + SiLU -> xconv (overlays Win16)
    conv_silu_k<<<(B_ * L_ * DI) / 256, 256, 0, stream>>>(proj, convw, convb, xconv);

    // 3) x_dbl = xconv @ Wx^T   (N=160, K=4096)  [fp32]
    gemm_nt<0><<<dim3(3, M / 64), 256, 0, stream>>>(
        xconv, DI, Wx, DI, xdbl, 160, 160, DI, nullptr);

    // 4) delta = softplus(dt @ Wdt^T + bdt)   (N=4096, K=128)  [fp32]
    gemm_nt<1><<<dim3(DI / 64, M / 64), 256, 0, stream>>>(
        xdbl, 160, Wdt, RR, dlt, DI, DI, RR, bdt);

    // 5) selective scan + D-skip + SiLU(z) gate -> y16 (overlays hs16)
    scan_k<<<512, 256, 0, stream>>>(dlt, xconv, xdbl, proj, Alog, Dp, y16);

    // cast Wout -> Wout16 (overlays dlt, dead after scan)
    cast_bf16_k<<<(DM * DI / 8 + 255) / 256, 256, 0, stream>>>(Wout, Wout16, DM * DI / 8);

    // 6) out = y @ Wout^T   (M=2048, N=2048, K=4096)  [bf16 MFMA]
    gemm_bf16_mfma<<<dim3(DM / 128, M / 128), 256, 0, stream>>>(
        y16, Wout16, out, DM, DI);
}

// Round 9
// 807.338 us; speedup vs baseline: 3.3517x; 1.8189x over previous
//
#include <hip/hip_runtime.h>
#include <cstdint>
#include <cstddef>

#define B_  2
#define L_  1024
#define DM  2048
#define DI  4096
#define RR  128
#define UNR 8

using short8 = __attribute__((ext_vector_type(8))) short;
using f32x4  = __attribute__((ext_vector_type(4))) float;

__device__ __forceinline__ float siluf(float v) {
    return v / (1.f + __expf(-v));
}
__device__ __forceinline__ float softplusf(float v) {
    return fmaxf(v, 0.f) + log1pf(__expf(-fabsf(v)));
}
// fp32 -> bf16 bits, round-to-nearest-even (finite inputs)
__device__ __forceinline__ unsigned short f2bf(float f) {
    unsigned u = __builtin_bit_cast(unsigned, f);
    u += 0x7fffu + ((u >> 16) & 1u);
    return (unsigned short)(u >> 16);
}

// ---------------- cast fp32 -> bf16, 8 elems/thread ----------------
__global__ __launch_bounds__(256)
void cast_bf16_k(const float* __restrict__ s, unsigned short* __restrict__ d, int n8)
{
    const int i = blockIdx.x * 256 + threadIdx.x;
    if (i >= n8) return;
    const float4* sp = (const float4*)s;
    const float4 a = sp[2 * i];
    const float4 b = sp[2 * i + 1];
    short8 o;
    o[0] = (short)f2bf(a.x); o[1] = (short)f2bf(a.y);
    o[2] = (short)f2bf(a.z); o[3] = (short)f2bf(a.w);
    o[4] = (short)f2bf(b.x); o[5] = (short)f2bf(b.y);
    o[6] = (short)f2bf(b.z); o[7] = (short)f2bf(b.w);
    *(short8*)(d + (size_t)i * 8) = o;
}

// ---------------- bf16 MFMA GEMM (NT): C[m][n] = sum_k A[m][k]*B[n][k] ----------------
// 128x128 tile, BK=32, 256 threads (4 waves, 2x2 quadrants of 64x64),
// global_load_lds width=16 staging, mfma_f32_16x16x32_bf16.
__global__ __launch_bounds__(256)
void gemm_bf16_mfma(const unsigned short* __restrict__ A16,  // [M][K] bf16 bits
                    const unsigned short* __restrict__ B16,  // [N][K] bf16 bits
                    float* __restrict__ C, int ldc, int K)
{
    __shared__ unsigned short As[128 * 32];   // [row][k], 64 B/row, linear
    __shared__ unsigned short Bs[128 * 32];
    const int t  = threadIdx.x;
    const int w  = t >> 6;          // wave 0..3
    const int l  = t & 63;
    const int m0 = blockIdx.y * 128;
    const int n0 = blockIdx.x * 128;
    const int wr = w >> 1, wc = w & 1;       // 64x64 quadrant
    const int lm = l & 15, lk = l >> 4;      // fragment lane coords

    f32x4 acc[4][4] = {};

    for (int k0 = 0; k0 < K; k0 += 32) {
        #pragma unroll
        for (int i = 0; i < 2; ++i) {
            const int cb  = w * 2 + i;
            const int c   = cb * 64 + l;
            const int row = c >> 2, c16 = c & 3;
            const unsigned short* ga = A16 + (size_t)(m0 + row) * K + k0 + c16 * 8;
            const unsigned short* gb = B16 + (size_t)(n0 + row) * K + k0 + c16 * 8;
            __builtin_amdgcn_global_load_lds((const __attribute__((address_space(1))) void*)ga,
                                             (__attribute__((address_space(3))) void*)(As + cb * 512),
                                             16, 0, 0);
            __builtin_amdgcn_global_load_lds((const __attribute__((address_space(1))) void*)gb,
                                             (__attribute__((address_space(3))) void*)(Bs + cb * 512),
                                             16, 0, 0);
        }
        __syncthreads();   // compiler drains vmcnt before barrier

        short8 aF[4], bF[4];
        #pragma unroll
        for (int m = 0; m < 4; ++m)
            aF[m] = *(const short8*)(As + (wr * 64 + m * 16 + lm) * 32 + lk * 8);
        #pragma unroll
        for (int n = 0; n < 4; ++n)
            bF[n] = *(const short8*)(Bs + (wc * 64 + n * 16 + lm) * 32 + lk * 8);
        #pragma unroll
        for (int m = 0; m < 4; ++m)
            #pragma unroll
            for (int n = 0; n < 4; ++n)
                acc[m][n] = __builtin_amdgcn_mfma_f32_16x16x32_bf16(aF[m], bF[n], acc[m][n], 0, 0, 0);
        __syncthreads();
    }

    // C/D layout: col = lane&15, row = (lane>>4)*4 + reg
    const int cm = m0 + wr * 64 + (l >> 4) * 4;
    const int cn = n0 + wc * 64 + lm;
    #pragma unroll
    for (int m = 0; m < 4; ++m)
        #pragma unroll
        for (int n = 0; n < 4; ++n)
            #pragma unroll
            for (int r = 0; r < 4; ++r)
                C[(size_t)(cm + m * 16 + r) * ldc + cn + n * 16] = acc[m][n][r];
}

// ---------------- fp32 tiled GEMM (NT) for the small projections ----------------
template<int EPI>
__global__ __launch_bounds__(256)
void gemm_nt(const float* __restrict__ A, int lda,
             const float* __restrict__ Bw, int ldb,
             float* __restrict__ C, int ldc,
             int N, int K, const float* __restrict__ bias)
{
    __shared__ float As[16][64];
    __shared__ float Bs[16][64];
    const int t  = threadIdx.x;
    const int m0 = blockIdx.y * 64;
    const int n0 = blockIdx.x * 64;
    const int lr = t >> 2;
    const int lc = (t & 3) << 2;
    const int ty = t >> 4;
    const int tx = t & 15;
    float acc[4][4] = {};

    const float* aP = A  + (size_t)(m0 + lr) * lda + lc;
    const float* bP = Bw + (size_t)(n0 + lr) * ldb + lc;
    const bool bok = (n0 + lr) < N;

    for (int k0 = 0; k0 < K; k0 += 16) {
        float4 av = *(const float4*)(aP + k0);
        float4 bv = make_float4(0.f, 0.f, 0.f, 0.f);
        if (bok) bv = *(const float4*)(bP + k0);
        __syncthreads();
        As[lc+0][lr] = av.x; As[lc+1][lr] = av.y; As[lc+2][lr] = av.z; As[lc+3][lr] = av.w;
        Bs[lc+0][lr] = bv.x; Bs[lc+1][lr] = bv.y; Bs[lc+2][lr] = bv.z; Bs[lc+3][lr] = bv.w;
        __syncthreads();
        #pragma unroll
        for (int kk = 0; kk < 16; ++kk) {
            float4 a4 = *(const float4*)&As[kk][ty << 2];
            float4 b4 = *(const float4*)&Bs[kk][tx << 2];
            float a[4] = {a4.x, a4.y, a4.z, a4.w};
            float b[4] = {b4.x, b4.y, b4.z, b4.w};
            #pragma unroll
            for (int i = 0; i < 4; ++i)
                #pragma unroll
                for (int j = 0; j < 4; ++j)
                    acc[i][j] = fmaf(a[i], b[j], acc[i][j]);
        }
    }

    #pragma unroll
    for (int i = 0; i < 4; ++i) {
        const int m = m0 + (ty << 2) + i;
        const int n = n0 + (tx << 2);
        if (n < N) {
            float4 o;
            float* po = (float*)&o;
            #pragma unroll
            for (int j = 0; j < 4; ++j) {
                float v = acc[i][j];
                if (EPI == 1) v = softplusf(v + bias[n + j]);
                po[j] = v;
            }
            *(float4*)(C + (size_t)m * ldc + n) = o;
        }
    }
}

// ---------------- fp32 split-K GEMM (NT), atomicAdd epilogue ----------------
// k-range = [blockIdx.z*Kslice, +Kslice). C must be zeroed beforehand.
__global__ __launch_bounds__(256)
void gemm_nt_splitk(const float* __restrict__ A, int lda,
                    const float* __restrict__ Bw, int ldb,
                    float* __restrict__ C, int ldc,
                    int N, int Kslice)
{
    __shared__ float As[16][64];
    __shared__ float Bs[16][64];
    const int t  = threadIdx.x;
    const int m0 = blockIdx.y * 64;
    const int n0 = blockIdx.x * 64;
    const int kb = blockIdx.z * Kslice;
    const int lr = t >> 2;
    const int lc = (t & 3) << 2;
    const int ty = t >> 4;
    const int tx = t & 15;
    float acc[4][4] = {};

    const float* aP = A  + (size_t)(m0 + lr) * lda + lc + kb;
    const float* bP = Bw + (size_t)(n0 + lr) * ldb + lc + kb;
    const bool bok = (n0 + lr) < N;

    for (int k0 = 0; k0 < Kslice; k0 += 16) {
        float4 av = *(const float4*)(aP + k0);
        float4 bv = make_float4(0.f, 0.f, 0.f, 0.f);
        if (bok) bv = *(const float4*)(bP + k0);
        __syncthreads();
        As[lc+0][lr] = av.x; As[lc+1][lr] = av.y; As[lc+2][lr] = av.z; As[lc+3][lr] = av.w;
        Bs[lc+0][lr] = bv.x; Bs[lc+1][lr] = bv.y; Bs[lc+2][lr] = bv.z; Bs[lc+3][lr] = bv.w;
        __syncthreads();
        #pragma unroll
        for (int kk = 0; kk < 16; ++kk) {
            float4 a4 = *(const float4*)&As[kk][ty << 2];
            float4 b4 = *(const float4*)&Bs[kk][tx << 2];
            float a[4] = {a4.x, a4.y, a4.z, a4.w};
            float b[4] = {b4.x, b4.y, b4.z, b4.w};
            #pragma unroll
            for (int i = 0; i < 4; ++i)
                #pragma unroll
                for (int j = 0; j < 4; ++j)
                    acc[i][j] = fmaf(a[i], b[j], acc[i][j]);
        }
    }

    #pragma unroll
    for (int i = 0; i < 4; ++i) {
        const int m = m0 + (ty << 2) + i;
        const int n = n0 + (tx << 2);
        if (n < N) {
            #pragma unroll
            for (int j = 0; j < 4; ++j)
                atomicAdd(&C[(size_t)m * ldc + n + j], acc[i][j]);
        }
    }
}

// ---------------- depthwise causal conv(4) + bias + SiLU ----------------
__global__ __launch_bounds__(256)
void conv_silu_k(const float* __restrict__ proj, const float* __restrict__ w,
                 const float* __restrict__ bias, float* __restrict__ xconv)
{
    const int idx = blockIdx.x * 256 + threadIdx.x;
    const int d  = idx & (DI - 1);
    const int bl = idx >> 12;
    const int l  = bl & (L_ - 1);
    const float* pp = proj + (size_t)bl * (2 * DI) + d;
    float acc = bias[d];
    #pragma unroll
    for (int j = 0; j < 4; ++j) {
        const int ls = l - 3 + j;
        if (ls >= 0)
            acc = fmaf(w[(d << 2) + j], pp[(ptrdiff_t)(j - 3) * (2 * DI)], acc);
    }
    xconv[idx] = siluf(acc);
}

// ---------------- selective scan; 8-step unroll, ping-pong prefetch ----------------
// 16 lanes per (b,d) channel, lane = state n. Emits gated y as bf16.
__global__ __launch_bounds__(256)
void scan_k(const float* __restrict__ dlt,
            const float* __restrict__ xconv,
            const float* __restrict__ xdbl,
            const float* __restrict__ proj,     // z = proj[b,l,DI+d]
            const float* __restrict__ A_log,
            const float* __restrict__ Dp,
            unsigned short* __restrict__ y16)
{
    const int bi = blockIdx.x;            // 0..511
    const int b  = bi >> 8;
    const int t  = threadIdx.x;
    const int n  = t & 15;
    const int d  = ((bi & 255) << 4) + (t >> 4);

    const float An = -__expf(A_log[(d << 4) + n]);
    const float Dd = Dp[d];
    float h = 0.f;

    const float* pd = dlt   + (size_t)(b << 10) * DI + d;
    const float* pu = xconv + (size_t)(b << 10) * DI + d;
    const float* pb = xdbl  + (size_t)(b << 10) * 160 + 128 + n;
    const float* pc = pb + 16;
    const float* pz = proj  + (size_t)(b << 10) * (2 * DI) + DI + d;
    unsigned short* py = y16 + (size_t)(b << 10) * DI + d;

    float dvA[UNR], uuA[UNR], bnA[UNR], cnA[UNR], zzA[UNR];
    float dvB[UNR], uuB[UNR], bnB[UNR], cnB[UNR], zzB[UNR];

#define LOADG(G, L0)                                               \
    { _Pragma("unroll")                                            \
      for (int u = 0; u < UNR; ++u) {                              \
        const int ll = (L0) + u;                                   \
        dv##G[u] = pd[(size_t)ll * DI];                            \
        uu##G[u] = pu[(size_t)ll * DI];                            \
        bn##G[u] = pb[(size_t)ll * 160];                           \
        cn##G[u] = pc[(size_t)ll * 160];                           \
        zz##G[u] = pz[(size_t)ll * (2 * DI)];                      \
      } }

#define COMPG(G, L0)                                               \
    { _Pragma("unroll")                                            \
      for (int u = 0; u < UNR; ++u) {                              \
        const float dA = __expf(dv##G[u] * An);                    \
        h = fmaf(dA, h, dv##G[u] * uu##G[u] * bn##G[u]);           \
        float p = h * cn##G[u];                                    \
        p += __shfl_xor(p, 1);                                     \
        p += __shfl_xor(p, 2);                                     \
        p += __shfl_xor(p, 4);                                     \
        p += __shfl_xor(p, 8);                                     \
        if (n == 0)                                                \
            py[(size_t)((L0) + u) * DI] =                          \
                f2bf((p + uu##G[u] * Dd) * siluf(zz##G[u]));       \
      } }

    LOADG(A, 0)
    for (int l0 = 0; l0 < L_; l0 += 2 * UNR) {
        LOADG(B, l0 + UNR)
        COMPG(A, l0)
        if (l0 + 2 * UNR < L_) LOADG(A, l0 + 2 * UNR)
        COMPG(B, l0 + UNR)
    }
#undef LOADG
#undef COMPG
}

extern "C" void kernel_launch(void* const* d_in, const int* in_sizes, int n_in,
                              void* d_out, int out_size, void* d_ws, size_t ws_size,
                              hipStream_t stream)
{
    const float* hs    = (const float*)d_in[1];
    const float* Win   = (const float*)d_in[2];
    const float* convw = (const float*)d_in[3];
    const float* convb = (const float*)d_in[4];
    const float* Wx    = (const float*)d_in[5];
    const float* Wdt   = (const float*)d_in[6];
    const float* bdt   = (const float*)d_in[7];
    const float* Wout  = (const float*)d_in[8];
    const float* Alog  = (const float*)d_in[9];
    const float* Dp    = (const float*)d_in[10];

    float* out  = (float*)d_out;                    // (2,1024,2048)
    float* proj = out + (size_t)B_ * L_ * DM;       // (2,1024,8192) = output 1

    // ws overlays (stream-ordered lifetimes):
    //  o0: Win16 (33.5MB, dead after in_proj) -> xconv fp32 (33.5MB)
    //  o1: xdbl fp32 (1.31MB)
    //  o2: delta fp32 (33.5MB, dead after scan) -> Wout16 (16.8MB)
    //  o3: hs16 (8.4MB, dead after in_proj) -> y16 (16.8MB)
    char* ws = (char*)d_ws;
    unsigned short* Win16  = (unsigned short*)ws;
    float*          xconv  = (float*)ws;
    float*          xdbl   = (float*)(ws + 33554432);
    float*          dlt    = (float*)(ws + 34865152);
    unsigned short* Wout16 = (unsigned short*)(ws + 34865152);
    unsigned short* hs16   = (unsigned short*)(ws + 68419584);
    unsigned short* y16    = (unsigned short*)(ws + 68419584);

    const int M = B_ * L_;   // 2048

    // casts for in_proj
    cast_bf16_k<<<(M * DM / 8 + 255) / 256, 256, 0, stream>>>(hs, hs16, M * DM / 8);
    cast_bf16_k<<<(2 * DI * DM / 8 + 255) / 256, 256, 0, stream>>>(Win, Win16, 2 * DI * DM / 8);

    // 1) proj = hs @ Win^T   (M=2048, N=8192, K=2048)  [bf16 MFMA]
    gemm_bf16_mfma<<<dim3((2 * DI) / 128, M / 128), 256, 0, stream>>>(
        hs16, Win16, proj, 2 * DI, DM);

    // 2) depthwise conv + bias + SiLU -> xconv (overlays Win16)
    conv_silu_k<<<(B_ * L_ * DI) / 256, 256, 0, stream>>>(proj, convw, convb, xconv);

    // 3) x_dbl = xconv @ Wx^T   (N=160, K=4096)  [fp32 split-K x8, atomic]
    hipMemsetAsync(xdbl, 0, (size_t)M * 160 * sizeof(float), stream);
    gemm_nt_splitk<<<dim3(3, M / 64, 8), 256, 0, stream>>>(
        xconv, DI, Wx, DI, xdbl, 160, 160, DI / 8);

    // 4) delta = softplus(dt @ Wdt^T + bdt)   (N=4096, K=128)  [fp32]
    gemm_nt<1><<<dim3(DI / 64, M / 64), 256, 0, stream>>>(
        xdbl, 160, Wdt, RR, dlt, DI, DI, RR, bdt);

    // 5) selective scan + D-skip + SiLU(z) gate -> y16 (overlays hs16)
    scan_k<<<512, 256, 0, stream>>>(dlt, xconv, xdbl, proj, Alog, Dp, y16);

    // cast Wout -> Wout16 (overlays dlt, dead after scan)
    cast_bf16_k<<<(DM * DI / 8 + 255) / 256, 256, 0, stream>>>(Wout, Wout16, DM * DI / 8);

    // 6) out = y @ Wout^T   (M=2048, N=2048, K=4096)  [bf16 MFMA]
    gemm_bf16_mfma<<<dim3(DM / 128, M / 128), 256, 0, stream>>>(
        y16, Wout16, out, DM, DI);
}

// Round 10
// 795.629 us; speedup vs baseline: 3.4010x; 1.0147x over previous
//
#include <hip/hip_runtime.h>
#include <cstdint>
#include <cstddef>

#define B_  2
#define L_  1024
#define DM  2048
#define DI  4096
#define RR  128
#define W_  64
#define NW  (L_ / W_)

using short8 = __attribute__((ext_vector_type(8))) short;
using f32x4  = __attribute__((ext_vector_type(4))) float;

__device__ __forceinline__ float siluf(float v) {
    return v / (1.f + __expf(-v));
}
__device__ __forceinline__ float softplusf(float v) {
    return fmaxf(v, 0.f) + log1pf(__expf(-fabsf(v)));
}
// fp32 -> bf16 bits, round-to-nearest-even (finite inputs)
__device__ __forceinline__ unsigned short f2bf(float f) {
    unsigned u = __builtin_bit_cast(unsigned, f);
    u += 0x7fffu + ((u >> 16) & 1u);
    return (unsigned short)(u >> 16);
}

// ---------------- cast fp32 -> bf16, 8 elems/thread ----------------
__global__ __launch_bounds__(256)
void cast_bf16_k(const float* __restrict__ s, unsigned short* __restrict__ d, int n8)
{
    const int i = blockIdx.x * 256 + threadIdx.x;
    if (i >= n8) return;
    const float4* sp = (const float4*)s;
    const float4 a = sp[2 * i];
    const float4 b = sp[2 * i + 1];
    short8 o;
    o[0] = (short)f2bf(a.x); o[1] = (short)f2bf(a.y);
    o[2] = (short)f2bf(a.z); o[3] = (short)f2bf(a.w);
    o[4] = (short)f2bf(b.x); o[5] = (short)f2bf(b.y);
    o[6] = (short)f2bf(b.z); o[7] = (short)f2bf(b.w);
    *(short8*)(d + (size_t)i * 8) = o;
}

// ---------------- bf16 MFMA GEMM (NT): C[m][n] = sum_k A[m][k]*B[n][k] ----------------
// 128x128 tile, BK=32, 256 threads (4 waves, 2x2 quadrants of 64x64),
// global_load_lds width=16 staging, mfma_f32_16x16x32_bf16.
__global__ __launch_bounds__(256)
void gemm_bf16_mfma(const unsigned short* __restrict__ A16,  // [M][K] bf16 bits
                    const unsigned short* __restrict__ B16,  // [N][K] bf16 bits
                    float* __restrict__ C, int ldc, int K)
{
    __shared__ unsigned short As[128 * 32];   // [row][k], 64 B/row, linear
    __shared__ unsigned short Bs[128 * 32];
    const int t  = threadIdx.x;
    const int w  = t >> 6;          // wave 0..3
    const int l  = t & 63;
    const int m0 = blockIdx.y * 128;
    const int n0 = blockIdx.x * 128;
    const int wr = w >> 1, wc = w & 1;       // 64x64 quadrant
    const int lm = l & 15, lk = l >> 4;      // fragment lane coords

    f32x4 acc[4][4] = {};

    for (int k0 = 0; k0 < K; k0 += 32) {
        #pragma unroll
        for (int i = 0; i < 2; ++i) {
            const int cb  = w * 2 + i;
            const int c   = cb * 64 + l;
            const int row = c >> 2, c16 = c & 3;
            const unsigned short* ga = A16 + (size_t)(m0 + row) * K + k0 + c16 * 8;
            const unsigned short* gb = B16 + (size_t)(n0 + row) * K + k0 + c16 * 8;
            __builtin_amdgcn_global_load_lds((const __attribute__((address_space(1))) void*)ga,
                                             (__attribute__((address_space(3))) void*)(As + cb * 512),
                                             16, 0, 0);
            __builtin_amdgcn_global_load_lds((const __attribute__((address_space(1))) void*)gb,
                                             (__attribute__((address_space(3))) void*)(Bs + cb * 512),
                                             16, 0, 0);
        }
        __syncthreads();   // compiler drains vmcnt before barrier

        short8 aF[4], bF[4];
        #pragma unroll
        for (int m = 0; m < 4; ++m)
            aF[m] = *(const short8*)(As + (wr * 64 + m * 16 + lm) * 32 + lk * 8);
        #pragma unroll
        for (int n = 0; n < 4; ++n)
            bF[n] = *(const short8*)(Bs + (wc * 64 + n * 16 + lm) * 32 + lk * 8);
        #pragma unroll
        for (int m = 0; m < 4; ++m)
            #pragma unroll
            for (int n = 0; n < 4; ++n)
                acc[m][n] = __builtin_amdgcn_mfma_f32_16x16x32_bf16(aF[m], bF[n], acc[m][n], 0, 0, 0);
        __syncthreads();
    }

    // C/D layout: col = lane&15, row = (lane>>4)*4 + reg
    const int cm = m0 + wr * 64 + (l >> 4) * 4;
    const int cn = n0 + wc * 64 + lm;
    #pragma unroll
    for (int m = 0; m < 4; ++m)
        #pragma unroll
        for (int n = 0; n < 4; ++n)
            #pragma unroll
            for (int r = 0; r < 4; ++r)
                C[(size_t)(cm + m * 16 + r) * ldc + cn + n * 16] = acc[m][n][r];
}

// ---------------- fp32 tiled GEMM (NT) for the small projections ----------------
template<int EPI>
__global__ __launch_bounds__(256)
void gemm_nt(const float* __restrict__ A, int lda,
             const float* __restrict__ Bw, int ldb,
             float* __restrict__ C, int ldc,
             int N, int K, const float* __restrict__ bias)
{
    __shared__ float As[16][64];
    __shared__ float Bs[16][64];
    const int t  = threadIdx.x;
    const int m0 = blockIdx.y * 64;
    const int n0 = blockIdx.x * 64;
    const int lr = t >> 2;
    const int lc = (t & 3) << 2;
    const int ty = t >> 4;
    const int tx = t & 15;
    float acc[4][4] = {};

    const float* aP = A  + (size_t)(m0 + lr) * lda + lc;
    const float* bP = Bw + (size_t)(n0 + lr) * ldb + lc;
    const bool bok = (n0 + lr) < N;

    for (int k0 = 0; k0 < K; k0 += 16) {
        float4 av = *(const float4*)(aP + k0);
        float4 bv = make_float4(0.f, 0.f, 0.f, 0.f);
        if (bok) bv = *(const float4*)(bP + k0);
        __syncthreads();
        As[lc+0][lr] = av.x; As[lc+1][lr] = av.y; As[lc+2][lr] = av.z; As[lc+3][lr] = av.w;
        Bs[lc+0][lr] = bv.x; Bs[lc+1][lr] = bv.y; Bs[lc+2][lr] = bv.z; Bs[lc+3][lr] = bv.w;
        __syncthreads();
        #pragma unroll
        for (int kk = 0; kk < 16; ++kk) {
            float4 a4 = *(const float4*)&As[kk][ty << 2];
            float4 b4 = *(const float4*)&Bs[kk][tx << 2];
            float a[4] = {a4.x, a4.y, a4.z, a4.w};
            float b[4] = {b4.x, b4.y, b4.z, b4.w};
            #pragma unroll
            for (int i = 0; i < 4; ++i)
                #pragma unroll
                for (int j = 0; j < 4; ++j)
                    acc[i][j] = fmaf(a[i], b[j], acc[i][j]);
        }
    }

    #pragma unroll
    for (int i = 0; i < 4; ++i) {
        const int m = m0 + (ty << 2) + i;
        const int n = n0 + (tx << 2);
        if (n < N) {
            float4 o;
            float* po = (float*)&o;
            #pragma unroll
            for (int j = 0; j < 4; ++j) {
                float v = acc[i][j];
                if (EPI == 1) v = softplusf(v + bias[n + j]);
                po[j] = v;
            }
            *(float4*)(C + (size_t)m * ldc + n) = o;
        }
    }
}

// ---------------- fp32 split-K GEMM (NT), atomicAdd epilogue ----------------
// k-range = [blockIdx.z*Kslice, +Kslice). C must be zeroed beforehand.
__global__ __launch_bounds__(256)
void gemm_nt_splitk(const float* __restrict__ A, int lda,
                    const float* __restrict__ Bw, int ldb,
                    float* __restrict__ C, int ldc,
                    int N, int Kslice)
{
    __shared__ float As[16][64];
    __shared__ float Bs[16][64];
    const int t  = threadIdx.x;
    const int m0 = blockIdx.y * 64;
    const int n0 = blockIdx.x * 64;
    const int kb = blockIdx.z * Kslice;
    const int lr = t >> 2;
    const int lc = (t & 3) << 2;
    const int ty = t >> 4;
    const int tx = t & 15;
    float acc[4][4] = {};

    const float* aP = A  + (size_t)(m0 + lr) * lda + lc + kb;
    const float* bP = Bw + (size_t)(n0 + lr) * ldb + lc + kb;
    const bool bok = (n0 + lr) < N;

    for (int k0 = 0; k0 < Kslice; k0 += 16) {
        float4 av = *(const float4*)(aP + k0);
        float4 bv = make_float4(0.f, 0.f, 0.f, 0.f);
        if (bok) bv = *(const float4*)(bP + k0);
        __syncthreads();
        As[lc+0][lr] = av.x; As[lc+1][lr] = av.y; As[lc+2][lr] = av.z; As[lc+3][lr] = av.w;
        Bs[lc+0][lr] = bv.x; Bs[lc+1][lr] = bv.y; Bs[lc+2][lr] = bv.z; Bs[lc+3][lr] = bv.w;
        __syncthreads();
        #pragma unroll
        for (int kk = 0; kk < 16; ++kk) {
            float4 a4 = *(const float4*)&As[kk][ty << 2];
            float4 b4 = *(const float4*)&Bs[kk][tx << 2];
            float a[4] = {a4.x, a4.y, a4.z, a4.w};
            float b[4] = {b4.x, b4.y, b4.z, b4.w};
            #pragma unroll
            for (int i = 0; i < 4; ++i)
                #pragma unroll
                for (int j = 0; j < 4; ++j)
                    acc[i][j] = fmaf(a[i], b[j], acc[i][j]);
        }
    }

    #pragma unroll
    for (int i = 0; i < 4; ++i) {
        const int m = m0 + (ty << 2) + i;
        const int n = n0 + (tx << 2);
        if (n < N) {
            #pragma unroll
            for (int j = 0; j < 4; ++j)
                atomicAdd(&C[(size_t)m * ldc + n + j], acc[i][j]);
        }
    }
}

// ---------------- depthwise causal conv(4) + bias + SiLU ----------------
__global__ __launch_bounds__(256)
void conv_silu_k(const float* __restrict__ proj, const float* __restrict__ w,
                 const float* __restrict__ bias, float* __restrict__ xconv)
{
    const int idx = blockIdx.x * 256 + threadIdx.x;
    const int d  = idx & (DI - 1);
    const int bl = idx >> 12;
    const int l  = bl & (L_ - 1);
    const float* pp = proj + (size_t)bl * (2 * DI) + d;
    float acc = bias[d];
    #pragma unroll
    for (int j = 0; j < 4; ++j) {
        const int ls = l - 3 + j;
        if (ls >= 0)
            acc = fmaf(w[(d << 2) + j], pp[(ptrdiff_t)(j - 3) * (2 * DI)], acc);
    }
    xconv[idx] = siluf(acc);
}

// ---------------- selective scan; LDS window staging (W_=64, double-buffered) ----------------
// 16 lanes per (b,d) channel, lane = state n. Emits gated y as bf16.
// Staging: thread t loads one float4 per stream per window (row=t>>2, quad=t&3),
// global->reg before compute phase, reg->LDS + 1 barrier after (T14 pattern).
__global__ __launch_bounds__(256)
void scan_k(const float* __restrict__ dlt,
            const float* __restrict__ xconv,
            const float* __restrict__ xdbl,
            const float* __restrict__ proj,     // z = proj[b,l,DI+d]
            const float* __restrict__ A_log,
            const float* __restrict__ Dp,
            unsigned short* __restrict__ y16)
{
    const int bi = blockIdx.x;            // 0..511
    const int b  = bi >> 8;
    const int t  = threadIdx.x;
    const int n  = t & 15;                // state index
    const int ch = t >> 4;                // 0..15 channel-in-block
    const int d0 = (bi & 255) << 4;
    const int d  = d0 + ch;

    __shared__ float dvS[2][W_][16];
    __shared__ float uuS[2][W_][16];
    __shared__ float bnS[2][W_][16];
    __shared__ float cnS[2][W_][16];
    __shared__ float zzS[2][W_][16];

    const float An = -__expf(A_log[(d << 4) + n]);
    const float Dd = Dp[d];
    float h = 0.f;

    // staging coords: one float4 per stream per thread per window
    const int srow = t >> 2;              // 0..63 step within window
    const int sq   = (t & 3) << 2;        // 0,4,8,12 column
    const size_t bl0 = (size_t)(b << 10);

    const float* gdv = dlt   + (bl0 + srow) * DI + d0 + sq;
    const float* guu = xconv + (bl0 + srow) * DI + d0 + sq;
    const float* gbn = xdbl  + (bl0 + srow) * 160 + 128 + sq;
    const float* gcn = gbn + 16;
    const float* gzz = proj  + (bl0 + srow) * (2 * DI) + DI + d0 + sq;

    unsigned short* py = y16 + bl0 * DI + d;

    float4 rdv, ruu, rbn, rcn, rzz;

#define LOADW(l0)                                                    \
    { rdv = *(const float4*)(gdv + (size_t)(l0) * DI);               \
      ruu = *(const float4*)(guu + (size_t)(l0) * DI);               \
      rbn = *(const float4*)(gbn + (size_t)(l0) * 160);              \
      rcn = *(const float4*)(gcn + (size_t)(l0) * 160);              \
      rzz = *(const float4*)(gzz + (size_t)(l0) * (2 * DI)); }

#define WRITEW(s)                                                    \
    { *(float4*)&dvS[s][srow][sq] = rdv;                             \
      *(float4*)&uuS[s][srow][sq] = ruu;                             \
      *(float4*)&bnS[s][srow][sq] = rbn;                             \
      *(float4*)&cnS[s][srow][sq] = rcn;                             \
      *(float4*)&zzS[s][srow][sq] = rzz; }

#define COMPW(s, l0)                                                 \
    for (int w8 = 0; w8 < W_; w8 += 8) {                             \
      _Pragma("unroll")                                              \
      for (int u = 0; u < 8; ++u) {                                  \
        const int st = w8 + u;                                       \
        const float dv = dvS[s][st][ch];                             \
        const float uu = uuS[s][st][ch];                             \
        const float bn = bnS[s][st][n];                              \
        const float cn = cnS[s][st][n];                              \
        const float dA = __expf(dv * An);                            \
        h = fmaf(dA, h, dv * uu * bn);                               \
        float p = h * cn;                                            \
        p += __shfl_xor(p, 1);                                       \
        p += __shfl_xor(p, 2);                                       \
        p += __shfl_xor(p, 4);                                       \
        p += __shfl_xor(p, 8);                                       \
        if (n == 0) {                                                \
            const float zz = zzS[s][st][ch];                         \
            py[(size_t)((l0) + st) * DI] =                           \
                f2bf((p + uu * Dd) * siluf(zz));                     \
        }                                                            \
      }                                                              \
    }

    LOADW(0);
    WRITEW(0);
    __syncthreads();
    int s = 0;
    for (int wnd = 0; wnd < NW; ++wnd) {
        if (wnd + 1 < NW) LOADW((wnd + 1) * W_);   // global->reg, in flight during compute
        COMPW(s, wnd * W_);
        if (wnd + 1 < NW) {
            WRITEW(s ^ 1);                          // other buffer: safe pre-barrier
            __syncthreads();
        }
        s ^= 1;
    }
#undef LOADW
#undef WRITEW
#undef COMPW
}

extern "C" void kernel_launch(void* const* d_in, const int* in_sizes, int n_in,
                              void* d_out, int out_size, void* d_ws, size_t ws_size,
                              hipStream_t stream)
{
    const float* hs    = (const float*)d_in[1];
    const float* Win   = (const float*)d_in[2];
    const float* convw = (const float*)d_in[3];
    const float* convb = (const float*)d_in[4];
    const float* Wx    = (const float*)d_in[5];
    const float* Wdt   = (const float*)d_in[6];
    const float* bdt   = (const float*)d_in[7];
    const float* Wout  = (const float*)d_in[8];
    const float* Alog  = (const float*)d_in[9];
    const float* Dp    = (const float*)d_in[10];

    float* out  = (float*)d_out;                    // (2,1024,2048)
    float* proj = out + (size_t)B_ * L_ * DM;       // (2,1024,8192) = output 1

    // ws overlays (stream-ordered lifetimes):
    //  o0: Win16 (33.5MB, dead after in_proj) -> xconv fp32 (33.5MB)
    //  o1: xdbl fp32 (1.31MB)
    //  o2: delta fp32 (33.5MB, dead after scan) -> Wout16 (16.8MB)
    //  o3: hs16 (8.4MB, dead after in_proj) -> y16 (16.8MB)
    char* ws = (char*)d_ws;
    unsigned short* Win16  = (unsigned short*)ws;
    float*          xconv  = (float*)ws;
    float*          xdbl   = (float*)(ws + 33554432);
    float*          dlt    = (float*)(ws + 34865152);
    unsigned short* Wout16 = (unsigned short*)(ws + 34865152);
    unsigned short* hs16   = (unsigned short*)(ws + 68419584);
    unsigned short* y16    = (unsigned short*)(ws + 68419584);

    const int M = B_ * L_;   // 2048

    // casts for in_proj
    cast_bf16_k<<<(M * DM / 8 + 255) / 256, 256, 0, stream>>>(hs, hs16, M * DM / 8);
    cast_bf16_k<<<(2 * DI * DM / 8 + 255) / 256, 256, 0, stream>>>(Win, Win16, 2 * DI * DM / 8);

    // 1) proj = hs @ Win^T   (M=2048, N=8192, K=2048)  [bf16 MFMA]
    gemm_bf16_mfma<<<dim3((2 * DI) / 128, M / 128), 256, 0, stream>>>(
        hs16, Win16, proj, 2 * DI, DM);

    // 2) depthwise conv + bias + SiLU -> xconv (overlays Win16)
    conv_silu_k<<<(B_ * L_ * DI) / 256, 256, 0, stream>>>(proj, convw, convb, xconv);

    // 3) x_dbl = xconv @ Wx^T   (N=160, K=4096)  [fp32 split-K x8, atomic]
    hipMemsetAsync(xdbl, 0, (size_t)M * 160 * sizeof(float), stream);
    gemm_nt_splitk<<<dim3(3, M / 64, 8), 256, 0, stream>>>(
        xconv, DI, Wx, DI, xdbl, 160, 160, DI / 8);

    // 4) delta = softplus(dt @ Wdt^T + bdt)   (N=4096, K=128)  [fp32]
    gemm_nt<1><<<dim3(DI / 64, M / 64), 256, 0, stream>>>(
        xdbl, 160, Wdt, RR, dlt, DI, DI, RR, bdt);

    // 5) selective scan + D-skip + SiLU(z) gate -> y16 (overlays hs16)
    scan_k<<<512, 256, 0, stream>>>(dlt, xconv, xdbl, proj, Alog, Dp, y16);

    // cast Wout -> Wout16 (overlays dlt, dead after scan)
    cast_bf16_k<<<(DM * DI / 8 + 255) / 256, 256, 0, stream>>>(Wout, Wout16, DM * DI / 8);

    // 6) out = y @ Wout^T   (M=2048, N=2048, K=4096)  [bf16 MFMA]
    gemm_bf16_mfma<<<dim3(DM / 128, M / 128), 256, 0, stream>>>(
        y16, Wout16, out, DM, DI);
}